// Round 1
// 122.708 us; speedup vs baseline: 1.0265x; 1.0265x over previous
//
#include <hip/hip_runtime.h>

namespace {

constexpr int L           = 128;
constexpr int NANG        = 120;
constexpr int SLICE_BYTES = L * L * 4;   // 65536 = 1<<16
constexpr int ROW_BYTES   = L * 4;       // 512
constexpr int NPTS        = 16;          // 4x4 (x,y) tile

typedef __fp16 f16x2 __attribute__((ext_vector_type(2)));
typedef __fp16 f16x4 __attribute__((ext_vector_type(4)));
typedef float  f32x4 __attribute__((ext_vector_type(4)));

// Block: 512 thr = 8 waves. Tile: 4(x) x 4(y) = 16 points, both b, all 128 z.
// Wave w: b = w&1, zq2 = w>>1 (32-z quarter).
// K-packing: one 16x16x16 MFMA holds TWO angles (8-row windows): quads 0,1 ->
// angle 2p (k 0-7), quads 2,3 -> angle 2p+1 (k 8-15). 4x4 tile sy-span <= ~6.2
// rows, so an 8-row window with -1 margin always covers all nonzero weights.
// z remap z = zq2*32 + 2*n + i: B-loads are dwordx2, C-stores are float2.
// A-fragments precomputed in LDS; per angle-pair the main loop is only
// 2 ds_read + 1 v_add + 4 global_load_dwordx2 + 4 cvt_pkrtz + 2 MFMA.
// Grid 1024 = 4 blocks/CU -> 8 waves/SIMD (max occupancy).
__global__ __launch_bounds__(512, 8) void bp_kernel(
    const float* __restrict__ image,   // [2,120,128,128] f32
    const float* __restrict__ angles,  // [120] deg
    float* __restrict__ out)           // [2,128,128,128] f32
{
    __shared__ alignas(16) unsigned long long aftab[NANG * 2 * NPTS]; // 30 KiB: [a][lq][p]
    __shared__ float2   acs[NANG];
    __shared__ unsigned arloB[NANG];   // (window first row) << 9  (byte offset)
    __shared__ alignas(16) float nrmtab[NPTS];

    const int tid = threadIdx.x;
    // Bijective XCD swizzle: 1024 blocks = 8 XCDs x 128 -> each XCD gets a
    // contiguous x-slab of tiles for L2 window locality.
    const int swz = ((int)blockIdx.x & 7) * 128 + ((int)blockIdx.x >> 3);
    const int yb  = (swz & 31) * 4;
    const int xb  = (swz >> 5) * 4;
    const float cx = (L - 1) * 0.5f;

    // ---- Phase 0: per-angle rotation params + 8-row window floor ----
    if (tid < NANG) {
        const float phi = -angles[tid] * 0.017453292519943295f;
        float s, c;
        sincosf(phi, &s, &c);
        const float X0 = (float)xb - cx,  X1 = (float)(xb + 3) - cx;
        const float Y0 = (float)yb - cx,  Y1 = (float)(yb + 3) - cx;
        const float a00 = -s * X0 + c * Y0 + cx;
        const float a01 = -s * X0 + c * Y1 + cx;
        const float a10 = -s * X1 + c * Y0 + cx;
        const float a11 = -s * X1 + c * Y1 + cx;
        const float symin = fminf(fminf(a00, a01), fminf(a10, a11));
        acs[tid]   = make_float2(c, s);
        // span (incl. bilinear tap) <= 7 rows; -1 margin absorbs fp jitter;
        // rlo <= 120 keeps rows rlo..rlo+7 in-bounds always.
        arloB[tid] = (unsigned)min(max((int)floorf(symin) - 1, 0), 120) << 9;
    }
    if (tid < NPTS) nrmtab[tid] = 0.f;
    __syncthreads();

    // ---- Phase 1: precompute per-(angle,point) A-fragments (f16 w0,w1 placed
    //      into the 8-slot window, both K-halves) + norm partial sums ----
    float wsum = 0.f;
#pragma unroll
    for (int k = 0; k < 4; ++k) {
        const int e = tid + k * 512;            // e = a*16 + p  (p = tid&15 fixed)
        if (e < NANG * NPTS) {
            const int p = e & 15;
            const int a = e >> 4;
            const float2 cs = acs[a];
            const int rlo = (int)(arloB[a] >> 9);
            const float X = (float)(xb + (p >> 2)) - cx;
            const float Y = (float)(yb + (p & 3)) - cx;
            const float sx =  cs.x * X + cs.y * Y + cx;
            const float sy = -cs.y * X + cs.x * Y + cx;
            const float x0f = floorf(sx), y0f = floorf(sy);
            const float wx = sx - x0f,    wy = sy - y0f;
            const int x0 = (int)x0f, y0 = (int)y0f;
            const float mx0 = (x0 >= 0  && x0 <  L)     ? 1.f : 0.f;
            const float mx1 = (x0 >= -1 && x0 <= L - 2) ? 1.f : 0.f;
            const float my0 = (y0 >= 0  && y0 <  L)     ? 1.f : 0.f;
            const float my1 = (y0 >= -1 && y0 <= L - 2) ? 1.f : 0.f;
            const float A   = (1.f - wx) * mx0 + wx * mx1;
            float w0f = (1.f - wy) * my0 * A;
            float w1f = wy * my1 * A;
            const int y0c = min(max(y0, 0), L - 1);
            const int y1c = min(max(y0 + 1, 0), L - 1);
            const int s0  = min(max(y0c - rlo, 0), 7);
            const int s1  = min(max(y1c - rlo, 0), 7);
            // boundary clamp collision: fold w1 into w0 (exact: one mask is 0)
            if (s0 == s1) { w0f += w1f; w1f = 0.f; }
            f16x2 wh = __builtin_amdgcn_cvt_pkrtz(w0f, w1f);
            const unsigned wbits = *reinterpret_cast<unsigned*>(&wh);
            const unsigned t  = (unsigned)s0 & 3u;
            const int      q0 = s0 >> 2;                  // 0 or 1
            const unsigned long long W = (unsigned long long)wbits << (t * 16u);
            const unsigned long long spill =
                (t == 3u) ? (unsigned long long)(wbits >> 16) : 0ull;
            aftab[a * 32 + p]      = (q0 == 0) ? W : 0ull;      // lq=0 half
            aftab[a * 32 + 16 + p] = (q0 == 1) ? W : spill;     // lq=1 half
            wsum += w0f + w1f;
        }
    }
    atomicAdd(&nrmtab[tid & 15], wsum);   // 32 adds/address (was 120)
    __syncthreads();   // the ONLY barrier before the epilogue

    const int wave  = tid >> 6;
    const int lane  = tid & 63;
    const int quad  = lane >> 4;
    const int lhalf = lane & 15;
    const int sel   = quad >> 1;           // which angle of the pair
    const int lq    = quad & 1;            // which 4-row K-subgroup of its window
    const int b     = wave & 1;
    const int zq2   = wave >> 1;           // 0..3, 32 z's each
    const char* __restrict__ imgc = (const char*)image;

    const unsigned bbase_s = __builtin_amdgcn_readfirstlane((unsigned)(b * NANG) * SLICE_BYTES);
    // per-lane constant part of the load offset: angle-select + row-subgroup + z
    const unsigned voffc = (unsigned)sel * (unsigned)SLICE_BYTES
                         + (unsigned)(lq * 4) * ROW_BYTES
                         + (unsigned)(zq2 * 32 + 2 * lhalf) * 4u;

    f32x4 acc[2] = {};   // [i] : z parity

    auto read_af = [&](int pr) -> unsigned long long {
        // (2p+sel)*32 + lq*16 + lhalf == p*64 + lane : linear, conflict-free,
        // per-pair offset folds into the ds_read imm.
        return aftab[pr * 64 + lane];
    };
    auto read_rl = [&](int pr) -> unsigned {
        return arloB[2 * pr + sel];        // broadcast within each 32-lane half
    };
    auto issue = [&](int pr, unsigned rlB, float2* r) {
        const char* pa = imgc + (bbase_s + ((unsigned)(2 * pr) << 16)); // SGPR base
        const unsigned voff = voffc + rlB;
#pragma unroll
        for (int j = 0; j < 4; ++j)        // rows lq*4+j of slice 2p+sel, imm j*512
            r[j] = *(const float2*)(pa + (voff + (unsigned)(j * ROW_BYTES)));
    };
    auto compute = [&](unsigned long long afu, const float2* r) {
        union { unsigned long long u; f16x4 v; } c; c.u = afu;
        const f16x2 h0a = __builtin_amdgcn_cvt_pkrtz(r[0].x, r[1].x);
        const f16x2 h0b = __builtin_amdgcn_cvt_pkrtz(r[2].x, r[3].x);
        const f16x2 h1a = __builtin_amdgcn_cvt_pkrtz(r[0].y, r[1].y);
        const f16x2 h1b = __builtin_amdgcn_cvt_pkrtz(r[2].y, r[3].y);
        const f16x4 bf0 = {h0a.x, h0a.y, h0b.x, h0b.y};
        const f16x4 bf1 = {h1a.x, h1a.y, h1b.x, h1b.y};
        acc[0] = __builtin_amdgcn_mfma_f32_16x16x16f16(c.v, bf0, acc[0], 0, 0, 0);
        acc[1] = __builtin_amdgcn_mfma_f32_16x16x16f16(c.v, bf1, acc[1], 0, 0, 0);
    };

    // ---- Main loop: 3-buffer pipeline over 60 angle-pairs, prefetch depth 2 ----
    unsigned long long af0, af1, af2;
    unsigned rl0, rl1, rl2;
    float2 rb0[4], rb1[4], rb2[4];

    af0 = read_af(0); rl0 = read_rl(0); issue(0, rl0, rb0);
    af1 = read_af(1); rl1 = read_rl(1); issue(1, rl1, rb1);

    for (int p = 0; p < 60; p += 3) {
        if (p + 2 < 60) { af2 = read_af(p + 2); rl2 = read_rl(p + 2); issue(p + 2, rl2, rb2); }
        compute(af0, rb0);
        if (p + 3 < 60) { af0 = read_af(p + 3); rl0 = read_rl(p + 3); issue(p + 3, rl0, rb0); }
        compute(af1, rb1);
        if (p + 4 < 60) { af1 = read_af(p + 4); rl1 = read_rl(p + 4); issue(p + 4, rl1, rb1); }
        compute(af2, rb2);
    }

    // ---- Epilogue: D[row=quad*4+r][col=lhalf], point p = quad*4+r,
    //      z = zq2*32 + 2*lhalf + i  -> float2 store ----
    const float4 nrm4 = *(const float4*)&nrmtab[quad * 4];
    const float iv[4] = { 1.f / (nrm4.x + 1e-11f), 1.f / (nrm4.y + 1e-11f),
                          1.f / (nrm4.z + 1e-11f), 1.f / (nrm4.w + 1e-11f) };
    const int zb = zq2 * 32 + 2 * lhalf;
#pragma unroll
    for (int r = 0; r < 4; ++r) {
        const int pnt = quad * 4 + r;
        const int x = xb + (pnt >> 2);
        const int y = yb + (pnt & 3);
        const float2 o = make_float2(acc[0][r] * iv[r], acc[1][r] * iv[r]);
        *reinterpret_cast<float2*>(&out[(((size_t)(b * L + x)) * L + y) * L + zb]) = o;
    }
}

} // namespace

extern "C" void kernel_launch(void* const* d_in, const int* in_sizes, int n_in,
                              void* d_out, int out_size, void* d_ws, size_t ws_size,
                              hipStream_t stream) {
    const float* image  = (const float*)d_in[0];
    const float* angles = (const float*)d_in[1];
    float* out = (float*)d_out;
    (void)in_sizes; (void)n_in; (void)out_size; (void)d_ws; (void)ws_size;

    dim3 grid(1024);   // 32x32 tiles of 4x4 = exactly 4 blocks per CU
    bp_kernel<<<grid, 512, 0, stream>>>(image, angles, out);
}

// Round 2
// 101.984 us; speedup vs baseline: 1.2351x; 1.2032x over previous
//
#include <hip/hip_runtime.h>

namespace {

constexpr int L     = 128;
constexpr int NANG  = 120;
constexpr int NPTS  = 16;                 // 4x4 (x,y) tile
constexpr size_t H16_BYTES = (size_t)2 * NANG * L * L * 2;   // 7,864,320

typedef __fp16 f16x2 __attribute__((ext_vector_type(2)));
typedef __fp16 f16x4 __attribute__((ext_vector_type(4)));
typedef float  f32x4 __attribute__((ext_vector_type(4)));

// Prepass: image f32 -> f16 (round-toward-zero, identical bits to the main
// loop's former cvt_pkrtz of B) into workspace. 3840*256 threads * 4 elems.
__global__ __launch_bounds__(256) void cvt16_kernel(const float* __restrict__ in,
                                                    unsigned* __restrict__ out) {
    const int i = ((int)blockIdx.x * 256 + (int)threadIdx.x) * 4;
    const float4 v = *reinterpret_cast<const float4*>(in + i);
    f16x2 a = __builtin_amdgcn_cvt_pkrtz(v.x, v.y);
    f16x2 b = __builtin_amdgcn_cvt_pkrtz(v.z, v.w);
    uint2 st;
    st.x = *reinterpret_cast<unsigned*>(&a);
    st.y = *reinterpret_cast<unsigned*>(&b);
    *reinterpret_cast<uint2*>(out + i / 2) = st;
}

// Block: 512 thr = 8 waves. Tile: 4(x) x 4(y) = 16 points, both b, all 128 z.
// K-packing: one 16x16x16 MFMA holds TWO angles (8-row windows): quads 0,1 ->
// angle 2p, quads 2,3 -> angle 2p+1. Morton-chunked grid: XCD c owns Morton
// ids [128c,128c+128) = a 64x32-point rectangle, all co-resident -> per-angle
// row-window union (~63 rows) stays L2-hot, adjacent tiles share via L1.
// F16 path: image pre-converted to f16 (dword loads, v_perm B-frag assembly).
template <bool F16>
__global__ __launch_bounds__(512, 8) void bp_kernel(
    const void* __restrict__ imgv,     // f16: [2,120,128,128] half; f32: float
    const float* __restrict__ angles,  // [120] deg
    float* __restrict__ out)           // [2,128,128,128] f32
{
    constexpr unsigned SLICE = F16 ? 32768u : 65536u;
    constexpr unsigned ROWB  = F16 ? 256u  : 512u;
    constexpr int      RSH   = F16 ? 8 : 9;          // row -> byte shift

    __shared__ alignas(16) unsigned long long aftab[NANG * 2 * NPTS]; // 30 KiB
    __shared__ float2   acs[NANG];
    __shared__ unsigned arloB[NANG];   // (window first row) << RSH (byte offset)
    __shared__ alignas(16) float nrmtab[NPTS];

    const int tid = threadIdx.x;
    // Morton deinterleave of the per-XCD-contiguous id: bits 7..9 fixed per
    // chunk -> each XCD covers a 16x8-tile (64x32-point) rectangle.
    const int bid = (int)blockIdx.x;
    const int n   = ((bid & 7) << 7) | (bid >> 3);
    int xt = 0, yt = 0;
#pragma unroll
    for (int i = 0; i < 5; ++i) {
        xt |= ((n >> (2 * i)) & 1) << i;
        yt |= ((n >> (2 * i + 1)) & 1) << i;
    }
    const int xb = xt * 4, yb = yt * 4;
    const float cx = (L - 1) * 0.5f;

    // ---- Phase 0: per-angle rotation params + 8-row window floor ----
    if (tid < NANG) {
        const float phi = -angles[tid] * 0.017453292519943295f;
        float s, c;
        sincosf(phi, &s, &c);
        const float X0 = (float)xb - cx,  X1 = (float)(xb + 3) - cx;
        const float Y0 = (float)yb - cx,  Y1 = (float)(yb + 3) - cx;
        const float a00 = -s * X0 + c * Y0 + cx;
        const float a01 = -s * X0 + c * Y1 + cx;
        const float a10 = -s * X1 + c * Y0 + cx;
        const float a11 = -s * X1 + c * Y1 + cx;
        const float symin = fminf(fminf(a00, a01), fminf(a10, a11));
        acs[tid]   = make_float2(c, s);
        // 4x4 tile span (incl. bilinear tap) <= 7 rows; -1 margin; rlo <= 120
        // keeps rows rlo..rlo+7 in-bounds always.
        arloB[tid] = (unsigned)min(max((int)floorf(symin) - 1, 0), 120) << RSH;
    }
    if (tid < NPTS) nrmtab[tid] = 0.f;
    __syncthreads();

    // ---- Phase 1: per-(angle,point) A-fragments (f16 w0,w1 into the 8-slot
    //      window, both K-halves) + norm partial sums ----
    float wsum = 0.f;
#pragma unroll
    for (int k = 0; k < 4; ++k) {
        const int e = tid + k * 512;            // e = a*16 + p (p = tid&15 fixed)
        if (e < NANG * NPTS) {
            const int p = e & 15;
            const int a = e >> 4;
            const float2 cs = acs[a];
            const int rlo = (int)(arloB[a] >> RSH);
            const float X = (float)(xb + (p >> 2)) - cx;
            const float Y = (float)(yb + (p & 3)) - cx;
            const float sx =  cs.x * X + cs.y * Y + cx;
            const float sy = -cs.y * X + cs.x * Y + cx;
            const float x0f = floorf(sx), y0f = floorf(sy);
            const float wx = sx - x0f,    wy = sy - y0f;
            const int x0 = (int)x0f, y0 = (int)y0f;
            const float mx0 = (x0 >= 0  && x0 <  L)     ? 1.f : 0.f;
            const float mx1 = (x0 >= -1 && x0 <= L - 2) ? 1.f : 0.f;
            const float my0 = (y0 >= 0  && y0 <  L)     ? 1.f : 0.f;
            const float my1 = (y0 >= -1 && y0 <= L - 2) ? 1.f : 0.f;
            const float A   = (1.f - wx) * mx0 + wx * mx1;
            float w0f = (1.f - wy) * my0 * A;
            float w1f = wy * my1 * A;
            const int y0c = min(max(y0, 0), L - 1);
            const int y1c = min(max(y0 + 1, 0), L - 1);
            const int s0  = min(max(y0c - rlo, 0), 7);
            const int s1  = min(max(y1c - rlo, 0), 7);
            if (s0 == s1) { w0f += w1f; w1f = 0.f; }   // clamp collision fold
            f16x2 wh = __builtin_amdgcn_cvt_pkrtz(w0f, w1f);
            const unsigned wbits = *reinterpret_cast<unsigned*>(&wh);
            const unsigned t  = (unsigned)s0 & 3u;
            const int      q0 = s0 >> 2;                  // 0 or 1
            const unsigned long long W = (unsigned long long)wbits << (t * 16u);
            const unsigned long long spill =
                (t == 3u) ? (unsigned long long)(wbits >> 16) : 0ull;
            aftab[a * 32 + p]      = (q0 == 0) ? W : 0ull;      // lq=0 half
            aftab[a * 32 + 16 + p] = (q0 == 1) ? W : spill;     // lq=1 half
            wsum += w0f + w1f;
        }
    }
    atomicAdd(&nrmtab[tid & 15], wsum);
    __syncthreads();   // the ONLY barrier before the epilogue

    const int wave  = tid >> 6;
    const int lane  = tid & 63;
    const int quad  = lane >> 4;
    const int lhalf = lane & 15;
    const int sel   = quad >> 1;           // which angle of the pair
    const int lq    = quad & 1;            // which 4-row K-subgroup
    const int b     = wave & 1;
    const int zq2   = wave >> 1;           // 0..3, 32 z's each
    const char* __restrict__ imgc = (const char*)imgv;

    const unsigned bbase_s = __builtin_amdgcn_readfirstlane((unsigned)(b * NANG) * SLICE);
    const unsigned voffc = (unsigned)sel * SLICE
                         + (unsigned)(lq * 4) * ROWB
                         + (unsigned)(zq2 * 32 + 2 * lhalf) * (F16 ? 2u : 4u);

    f32x4 acc[2] = {};   // z parity

    // issue loads + table reads for angle pair pr into a slot
    auto issue = [&](unsigned* r, float2* rfp, unsigned long long& afs, int pr) {
        afs = aftab[pr * 64 + lane];           // linear, conflict-free ds_read
        const unsigned rlB = arloB[2 * pr + sel];
        const char* pa = imgc + (bbase_s + (unsigned)(2 * pr) * SLICE); // SGPR base
        const unsigned voff = voffc + rlB;
        if constexpr (F16) {
#pragma unroll
            for (int j = 0; j < 4; ++j)        // row lq*4+j, imm j*256
                r[j] = *(const unsigned*)(pa + (voff + (unsigned)j * ROWB));
        } else {
#pragma unroll
            for (int j = 0; j < 4; ++j)
                rfp[j] = *(const float2*)(pa + (voff + (unsigned)j * ROWB));
        }
    };
    auto compute = [&](const unsigned* r, const float2* rfp, unsigned long long afu) {
        union { unsigned long long u; f16x4 v; } c; c.u = afu;
        f16x4 bf0, bf1;
        if constexpr (F16) {
            // r[j] = f16[z even] | f16[z odd]<<16 for K-row j
            union { unsigned u[2]; f16x4 v; } b0, b1;
            b0.u[0] = __builtin_amdgcn_perm(r[1], r[0], 0x05040100u); // lo halves
            b0.u[1] = __builtin_amdgcn_perm(r[3], r[2], 0x05040100u);
            b1.u[0] = __builtin_amdgcn_perm(r[1], r[0], 0x07060302u); // hi halves
            b1.u[1] = __builtin_amdgcn_perm(r[3], r[2], 0x07060302u);
            bf0 = b0.v; bf1 = b1.v;
        } else {
            const f16x2 h0a = __builtin_amdgcn_cvt_pkrtz(rfp[0].x, rfp[1].x);
            const f16x2 h0b = __builtin_amdgcn_cvt_pkrtz(rfp[2].x, rfp[3].x);
            const f16x2 h1a = __builtin_amdgcn_cvt_pkrtz(rfp[0].y, rfp[1].y);
            const f16x2 h1b = __builtin_amdgcn_cvt_pkrtz(rfp[2].y, rfp[3].y);
            bf0 = f16x4{h0a.x, h0a.y, h0b.x, h0b.y};
            bf1 = f16x4{h1a.x, h1a.y, h1b.x, h1b.y};
        }
        acc[0] = __builtin_amdgcn_mfma_f32_16x16x16f16(c.v, bf0, acc[0], 0, 0, 0);
        acc[1] = __builtin_amdgcn_mfma_f32_16x16x16f16(c.v, bf1, acc[1], 0, 0, 0);
    };

    // ---- Main loop: 4-buffer pipeline over 60 angle-pairs, prefetch depth 3 ----
    unsigned ru0[4], ru1[4], ru2[4], ru3[4];
    float2   rf0[4], rf1[4], rf2[4], rf3[4];
    unsigned long long af0, af1, af2, af3;

    issue(ru0, rf0, af0, 0);
    issue(ru1, rf1, af1, 1);
    issue(ru2, rf2, af2, 2);

    for (int p = 0; p < 60; p += 4) {
        if (p + 3 < 60) issue(ru3, rf3, af3, p + 3);
        compute(ru0, rf0, af0);
        if (p + 4 < 60) issue(ru0, rf0, af0, p + 4);
        compute(ru1, rf1, af1);
        if (p + 5 < 60) issue(ru1, rf1, af1, p + 5);
        compute(ru2, rf2, af2);
        if (p + 6 < 60) issue(ru2, rf2, af2, p + 6);
        compute(ru3, rf3, af3);
    }

    // ---- Epilogue: D[row=quad*4+r][col=lhalf], point p = quad*4+r,
    //      z = zq2*32 + 2*lhalf + i -> float2 store ----
    const float4 nrm4 = *(const float4*)&nrmtab[quad * 4];
    const float iv[4] = { 1.f / (nrm4.x + 1e-11f), 1.f / (nrm4.y + 1e-11f),
                          1.f / (nrm4.z + 1e-11f), 1.f / (nrm4.w + 1e-11f) };
    const int zb = zq2 * 32 + 2 * lhalf;
#pragma unroll
    for (int r = 0; r < 4; ++r) {
        const int pnt = quad * 4 + r;
        const int x = xb + (pnt >> 2);
        const int y = yb + (pnt & 3);
        const float2 o = make_float2(acc[0][r] * iv[r], acc[1][r] * iv[r]);
        *reinterpret_cast<float2*>(&out[(((size_t)(b * L + x)) * L + y) * L + zb]) = o;
    }
}

} // namespace

extern "C" void kernel_launch(void* const* d_in, const int* in_sizes, int n_in,
                              void* d_out, int out_size, void* d_ws, size_t ws_size,
                              hipStream_t stream) {
    const float* image  = (const float*)d_in[0];
    const float* angles = (const float*)d_in[1];
    float* out = (float*)d_out;
    (void)in_sizes; (void)n_in; (void)out_size;

    dim3 grid(1024);   // 32x32 tiles of 4x4 = exactly 4 blocks per CU
    if (d_ws != nullptr && ws_size >= H16_BYTES) {
        cvt16_kernel<<<dim3(3840), 256, 0, stream>>>(image, (unsigned*)d_ws);
        bp_kernel<true><<<grid, 512, 0, stream>>>(d_ws, angles, out);
    } else {
        bp_kernel<false><<<grid, 512, 0, stream>>>(image, angles, out);
    }
}